// Round 2
// baseline (9873.532 us; speedup 1.0000x reference)
//
#include <hip/hip_runtime.h>
#include <hip/hip_bf16.h>
#include <math.h>

// Problem constants
#define DEPTH 4
#define D 512
#define H 8
#define DH 64
#define N 1024
#define M 1024
#define V 32000
#define BATCH 2
#define CTXLEN (M + N)         // 2048
#define ROWS (BATCH * N)       // 2048
#define CROWS (BATCH * CTXLEN) // 4096

typedef __hip_bfloat16 bf16;

static __device__ __forceinline__ float b2f(bf16 v) { return __bfloat162float(v); }

// dtype-agnostic load/store: f==1 -> fp32, f==0 -> bf16
static __device__ __forceinline__ float ldf(const void* p, size_t i, int f) {
    return f ? ((const float*)p)[i] : b2f(((const bf16*)p)[i]);
}
static __device__ __forceinline__ void stf(void* p, size_t i, int f, float v) {
    if (f) ((float*)p)[i] = v;
    else   ((bf16*)p)[i] = __float2bfloat16(v);
}

// ---------------- dtype detection ----------------
// Read first 1024 bf16-interpreted elements of tok_emb. bf16 data: all |v|<16
// (values ~N(0,0.02)) -> bad==0. fp32 data: even elements are fp32 mantissa
// halves -> random exponents -> bad ~125. flag=1 means fp32.
__global__ void detect_kernel(const void* __restrict__ p, int* __restrict__ flag,
                              float* __restrict__ aux) {
    __shared__ int cnt;
    if (threadIdx.x == 0) cnt = 0;
    __syncthreads();
    int bad = 0;
    for (int i = threadIdx.x; i < 1024; i += 256) {
        float v = b2f(((const bf16*)p)[i]);
        if (!(fabsf(v) < 16.0f)) bad++;   // NaN also counts as bad
    }
    if (bad) atomicAdd(&cnt, bad);
    __syncthreads();
    if (threadIdx.x == 0) *flag = (cnt >= 8) ? 1 : 0;
    if (threadIdx.x < BATCH) aux[threadIdx.x] = 0.0f;
}

// ---------------- embedding ----------------
__global__ __launch_bounds__(256) void embed_kernel(const int* __restrict__ tokens,
                                                    const void* __restrict__ emb,
                                                    float* __restrict__ x,
                                                    const int* __restrict__ dflag) {
    int f = *dflag;
    int row = blockIdx.x;                 // b*N + i
    int tok = tokens[row];
    float* xr = x + (size_t)row * D;
    for (int d = threadIdx.x; d < D; d += 256)
        xr[d] = ldf(emb, (size_t)tok * D + d, f);
}

// ---------------- sinusoidal embedding table ----------------
__global__ __launch_bounds__(256) void pe_kernel(float* __restrict__ pe) {
    int r = blockIdx.x;
    int k = threadIdx.x;                  // 0..255 (freq index)
    float t = (float)(N - 1 - r);
    float inv = expf(-(float)k * (9.210340371976184f / 256.0f)); // 10000^{-k/256}
    float s = t * inv;
    pe[(size_t)r * D + k]       = sinf(s);
    pe[(size_t)r * D + 256 + k] = cosf(s);
}

// ---------------- expire span gating (per layer) ----------------
__global__ __launch_bounds__(256) void expire_kernel(const void* __restrict__ mems,
                                                     size_t memOff,
                                                     const int* __restrict__ times_l,
                                                     const void* __restrict__ Wexp,
                                                     size_t wOff,
                                                     const void* __restrict__ bexp,
                                                     size_t bOff,
                                                     float* __restrict__ em,
                                                     float* __restrict__ aux,
                                                     const int* __restrict__ dflag) {
    int f = *dflag;
    int wave = (blockIdx.x * 256 + threadIdx.x) >> 6;  // global j over B*M
    int lane = threadIdx.x & 63;
    int b = wave / M, j = wave % M;
    size_t rbase = memOff + ((size_t)b * M + j) * D;
    float s = 0.0f;
    for (int d = lane; d < D; d += 64)
        s += ldf(mems, rbase + d, f) * ldf(Wexp, wOff + d, f);
    #pragma unroll
    for (int off = 32; off > 0; off >>= 1) s += __shfl_xor(s, off, 64);
    if (lane == 0) {
        s += ldf(bexp, bOff, f);
        float e = 1024.0f / (1.0f + expf(-s));      // sigmoid * MAXMEM
        float t = (float)times_l[b * M + j];
        float emv = (e - t) * (1.0f / 128.0f) + 1.0f;
        emv = fminf(fmaxf(emv, 0.0f), 1.0f);
        em[b * M + j] = emv;
        if (emv > 0.0f && emv < 1.0f)
            atomicAdd(&aux[b], e * (1.0f / (128.0f * 1024.0f)));
    }
}

// ---------------- ctx = concat(mem, x) fp32 ----------------
__global__ __launch_bounds__(256) void ctx_kernel(const void* __restrict__ mems,
                                                  size_t memOff,
                                                  const float* __restrict__ x,
                                                  float* __restrict__ ctx,
                                                  const int* __restrict__ dflag) {
    int f = *dflag;
    size_t idx = (size_t)blockIdx.x * 256 + threadIdx.x;  // over B*CTXLEN*D
    int d = idx & (D - 1);
    size_t rowg = idx >> 9;      // /D
    int p = rowg & (CTXLEN - 1);
    int b = rowg >> 11;          // /CTXLEN
    if (p < M) ctx[idx] = ldf(mems, memOff + ((size_t)b * M + p) * D + d, f);
    else       ctx[idx] = x[((size_t)b * N + (p - M)) * D + d];
}

// ---------------- generic tiled GEMM: C[M,N] = A[M,K](f32) * B[K,N](weights) + bias ----------------
// epi: 0 = store, 1 = C += acc+bias, 2 = gelu(acc+bias). Cb!=null -> store via stf (out dtype).
#define BM 64
#define BN 64
#define BK 16
__global__ __launch_bounds__(256) void gemm_kernel(int Mm, int Nn, int Kk,
                                                   const float* __restrict__ A,
                                                   const void* __restrict__ Bw, size_t bwOff,
                                                   const void* __restrict__ bias, size_t biasOff,
                                                   float* __restrict__ C,
                                                   void* __restrict__ Cb,
                                                   int epi,
                                                   const int* __restrict__ dflag) {
    int f = *dflag;
    __shared__ __align__(16) float As[BK][BM + 4];
    __shared__ __align__(16) float Bs[BK][BN + 4];
    int tid = threadIdx.x;
    int bm = blockIdx.y * BM;
    int bn = blockIdx.x * BN;
    int tx = tid & 15, ty = tid >> 4;
    int ka = tid & 15, ma = tid >> 4;   // A loads
    int nb = tid & 63, kb = tid >> 6;   // B loads
    float acc[4][4] = {};
    for (int k0 = 0; k0 < Kk; k0 += BK) {
        #pragma unroll
        for (int p = 0; p < 4; ++p)
            As[ka][ma + 16 * p] = A[(size_t)(bm + ma + 16 * p) * Kk + k0 + ka];
        #pragma unroll
        for (int p = 0; p < 4; ++p)
            Bs[kb + 4 * p][nb] = ldf(Bw, bwOff + (size_t)(k0 + kb + 4 * p) * Nn + bn + nb, f);
        __syncthreads();
        #pragma unroll
        for (int k = 0; k < BK; ++k) {
            float4 a4 = *(const float4*)&As[k][ty * 4];
            float4 b4 = *(const float4*)&Bs[k][tx * 4];
            float a[4] = {a4.x, a4.y, a4.z, a4.w};
            float b[4] = {b4.x, b4.y, b4.z, b4.w};
            #pragma unroll
            for (int i = 0; i < 4; ++i)
                #pragma unroll
                for (int j = 0; j < 4; ++j)
                    acc[i][j] += a[i] * b[j];
        }
        __syncthreads();
    }
    #pragma unroll
    for (int i = 0; i < 4; ++i) {
        int row = bm + ty * 4 + i;
        #pragma unroll
        for (int j = 0; j < 4; ++j) {
            int col = bn + tx * 4 + j;
            float v = acc[i][j];
            if (bias) v += ldf(bias, biasOff + col, f);
            size_t idx = (size_t)row * Nn + col;
            if (epi == 2) v = 0.5f * v * (1.0f + erff(v * 0.70710678118654752f));
            if (Cb) { stf(Cb, idx, f, v); }
            else {
                if (epi == 1) v += C[idx];
                C[idx] = v;
            }
        }
    }
}

// ---------------- attention: one wave per (b,h,i) ----------------
__global__ __launch_bounds__(64) void attn_kernel(const float* __restrict__ q,
                                                  const float* __restrict__ kv,
                                                  const float* __restrict__ pos,
                                                  const float* __restrict__ em,
                                                  float* __restrict__ outp) {
    __shared__ __align__(16) float w[CTXLEN];
    __shared__ __align__(16) float qs[DH];
    int bid = blockIdx.x;            // ((b*H)+h)*N + i
    int i = bid & (N - 1);
    int bh = bid >> 10;
    int h = bh & (H - 1);
    int b = bh >> 3;
    int lane = threadIdx.x;
    qs[lane] = q[((size_t)b * N + i) * D + h * DH + lane];
    __syncthreads();
    const int jmax = M + i;          // inclusive
    const float scale = 0.125f;      // DH^-0.5
    const float4* q4 = (const float4*)qs;
    float lmax = -1e30f;
    for (int j = lane; j <= jmax; j += 64) {
        const float4* k4 = (const float4*)(kv + ((size_t)b * CTXLEN + j) * (2 * D) + h * DH);
        float s = 0.0f;
        #pragma unroll
        for (int d = 0; d < DH / 4; ++d) {
            float4 kk = k4[d], qq = q4[d];
            s += qq.x * kk.x + qq.y * kk.y + qq.z * kk.z + qq.w * kk.w;
        }
        if (j >= M) {
            const float4* p4 = (const float4*)(pos + (size_t)(N - 1 - i + (j - M)) * DH);
            float sp = 0.0f;
            #pragma unroll
            for (int d = 0; d < DH / 4; ++d) {
                float4 pp = p4[d], qq = q4[d];
                sp += qq.x * pp.x + qq.y * pp.y + qq.z * pp.z + qq.w * pp.w;
            }
            s += sp;
        }
        s *= scale;
        w[j] = s;
        lmax = fmaxf(lmax, s);
    }
    #pragma unroll
    for (int off = 32; off > 0; off >>= 1) lmax = fmaxf(lmax, __shfl_xor(lmax, off, 64));
    __syncthreads();
    float lsum = 0.0f;
    for (int j = lane; j <= jmax; j += 64) {
        float e = expf(w[j] - lmax);
        lsum += e;                                   // denominator: plain softmax
        float g = (j < M) ? em[b * M + j] : 1.0f;    // post-softmax gate
        w[j] = e * g;
    }
    #pragma unroll
    for (int off = 32; off > 0; off >>= 1) lsum += __shfl_xor(lsum, off, 64);
    __syncthreads();
    const float* vcol = kv + (size_t)b * CTXLEN * (2 * D) + D + h * DH + lane;
    float acc = 0.0f;
    for (int j = 0; j <= jmax; ++j) acc += w[j] * vcol[(size_t)j * (2 * D)];
    outp[((size_t)b * N + i) * D + h * DH + lane] = acc / lsum;
}

// ---------------- final layernorm ----------------
__global__ __launch_bounds__(256) void ln_kernel(const float* __restrict__ x,
                                                 const void* __restrict__ g,
                                                 const void* __restrict__ bta,
                                                 float* __restrict__ y,
                                                 const int* __restrict__ dflag) {
    int f = *dflag;
    int row = blockIdx.x;
    const float* xr = x + (size_t)row * D;
    __shared__ float red[4];
    int lane = threadIdx.x & 63, wv = threadIdx.x >> 6;
    float s = 0.0f;
    for (int d = threadIdx.x; d < D; d += 256) s += xr[d];
    #pragma unroll
    for (int off = 32; off > 0; off >>= 1) s += __shfl_xor(s, off, 64);
    if (lane == 0) red[wv] = s;
    __syncthreads();
    float mu = (red[0] + red[1] + red[2] + red[3]) * (1.0f / D);
    __syncthreads();
    float v = 0.0f;
    for (int d = threadIdx.x; d < D; d += 256) { float t = xr[d] - mu; v += t * t; }
    #pragma unroll
    for (int off = 32; off > 0; off >>= 1) v += __shfl_xor(v, off, 64);
    if (lane == 0) red[wv] = v;
    __syncthreads();
    float var = (red[0] + red[1] + red[2] + red[3]) * (1.0f / D);
    float rstd = 1.0f / sqrtf(var + 1e-5f);
    for (int d = threadIdx.x; d < D; d += 256)
        y[(size_t)row * D + d] = (xr[d] - mu) * rstd * ldf(g, d, f) + ldf(bta, d, f);
}

// ---------------- aux write ----------------
__global__ void write_aux_kernel(const float* __restrict__ aux, void* __restrict__ out,
                                 const int* __restrict__ dflag) {
    int f = *dflag;
    if (threadIdx.x < BATCH)
        stf(out, (size_t)ROWS * V + threadIdx.x, f, aux[threadIdx.x]);
}

extern "C" void kernel_launch(void* const* d_in, const int* in_sizes, int n_in,
                              void* d_out, int out_size, void* d_ws, size_t ws_size,
                              hipStream_t stream) {
    (void)in_sizes; (void)n_in; (void)out_size; (void)ws_size;
    const int*  tokens  = (const int*)d_in[0];
    const void* mems    = d_in[1];
    const int*  times   = (const int*)d_in[2];
    const void* tok_emb = d_in[3];
    const void* Wq   = d_in[4];
    const void* bq   = d_in[5];
    const void* Wkv  = d_in[6];
    const void* bkv  = d_in[7];
    const void* Wo   = d_in[8];
    const void* bo   = d_in[9];
    const void* Wpos = d_in[10];
    const void* bpos = d_in[11];
    const void* Wexp = d_in[12];
    const void* bexp = d_in[13];
    const void* W1   = d_in[14];
    const void* b1   = d_in[15];
    const void* W2   = d_in[16];
    const void* b2v  = d_in[17];
    const void* ln_g = d_in[18];
    const void* ln_b = d_in[19];
    const void* Whead= d_in[20];

    float* ws  = (float*)d_ws;
    float* x    = ws;                            // ROWS*D   = 1,048,576
    float* pe   = x    + (size_t)ROWS * D;       // N*D      =   524,288
    float* ctx  = pe   + (size_t)N * D;          // CROWS*D  = 2,097,152 (y aliases)
    float* kv   = ctx  + (size_t)CROWS * D;      // CROWS*2D = 4,194,304 (h1 aliases)
    float* q    = kv   + (size_t)CROWS * 2 * D;  // ROWS*D   = 1,048,576
    float* pos  = q    + (size_t)ROWS * D;       // N*DH     =    65,536
    float* em   = pos  + (size_t)N * DH;         // B*M      =     2,048
    float* aout = em   + (size_t)BATCH * M;      // ROWS*D   = 1,048,576
    float* aux  = aout + (size_t)ROWS * D;       // 2
    int*   flag = (int*)(aux + 2);
    float* h1   = kv;   // alias: kv dead after attention, h1 dead before next kv
    float* y    = ctx;  // alias: ctx dead after final layer

    detect_kernel<<<1, 256, 0, stream>>>(tok_emb, flag, aux);
    embed_kernel<<<ROWS, 256, 0, stream>>>(tokens, tok_emb, x, flag);
    pe_kernel<<<N, 256, 0, stream>>>(pe);

    for (int l = 0; l < DEPTH; ++l) {
        expire_kernel<<<(BATCH * M) / 4, 256, 0, stream>>>(
            mems, (size_t)l * BATCH * M * D, times + (size_t)l * BATCH * M,
            Wexp, (size_t)l * D, bexp, (size_t)l, em, aux, flag);
        ctx_kernel<<<(BATCH * CTXLEN * D) / 256, 256, 0, stream>>>(
            mems, (size_t)l * BATCH * M * D, x, ctx, flag);
        // q = x @ Wq + bq        [ROWS,D]x[D,D]
        gemm_kernel<<<dim3(D / BN, ROWS / BM), 256, 0, stream>>>(
            ROWS, D, D, x, Wq, (size_t)l * D * D, bq, (size_t)l * D, q, nullptr, 0, flag);
        // kv = ctx @ Wkv + bkv   [CROWS,D]x[D,2D]
        gemm_kernel<<<dim3(2 * D / BN, CROWS / BM), 256, 0, stream>>>(
            CROWS, 2 * D, D, ctx, Wkv, (size_t)l * D * 2 * D, bkv, (size_t)l * 2 * D, kv, nullptr, 0, flag);
        // pos = pe @ Wpos + bpos [N,D]x[D,DH]
        gemm_kernel<<<dim3(DH / BN, N / BM), 256, 0, stream>>>(
            N, DH, D, pe, Wpos, (size_t)l * D * DH, bpos, (size_t)l * DH, pos, nullptr, 0, flag);
        // attention
        attn_kernel<<<BATCH * H * N, 64, 0, stream>>>(q, kv, pos, em, aout);
        // x += aout @ Wo + bo
        gemm_kernel<<<dim3(D / BN, ROWS / BM), 256, 0, stream>>>(
            ROWS, D, D, aout, Wo, (size_t)l * D * D, bo, (size_t)l * D, x, nullptr, 1, flag);
        // h1 = gelu(x @ W1 + b1)
        gemm_kernel<<<dim3(4 * D / BN, ROWS / BM), 256, 0, stream>>>(
            ROWS, 4 * D, D, x, W1, (size_t)l * D * 4 * D, b1, (size_t)l * 4 * D, h1, nullptr, 2, flag);
        // x += h1 @ W2 + b2
        gemm_kernel<<<dim3(D / BN, ROWS / BM), 256, 0, stream>>>(
            ROWS, D, 4 * D, h1, W2, (size_t)l * 4 * D * D, b2v, (size_t)l * D, x, nullptr, 1, flag);
    }

    ln_kernel<<<ROWS, 256, 0, stream>>>(x, ln_g, ln_b, y, flag);
    // logits = y @ Whead  -> out (dtype per flag)
    gemm_kernel<<<dim3(V / BN, ROWS / BM), 256, 0, stream>>>(
        ROWS, V, D, y, Whead, 0, nullptr, 0, nullptr, d_out, 0, flag);
    write_aux_kernel<<<1, 64, 0, stream>>>(aux, d_out, flag);
}

// Round 3
// 8234.142 us; speedup vs baseline: 1.1991x; 1.1991x over previous
//
#include <hip/hip_runtime.h>
#include <hip/hip_bf16.h>
#include <math.h>

// Problem constants
#define DEPTH 4
#define D 512
#define H 8
#define DH 64
#define N 1024
#define M 1024
#define V 32000
#define BATCH 2
#define CTXLEN (M + N)         // 2048
#define ROWS (BATCH * N)       // 2048
#define CROWS (BATCH * CTXLEN) // 4096

typedef __hip_bfloat16 bf16;

static __device__ __forceinline__ float b2f(bf16 v) { return __bfloat162float(v); }

// dtype-agnostic load/store: f==1 -> fp32, f==0 -> bf16
static __device__ __forceinline__ float ldf(const void* p, size_t i, int f) {
    return f ? ((const float*)p)[i] : b2f(((const bf16*)p)[i]);
}
static __device__ __forceinline__ void stf(void* p, size_t i, int f, float v) {
    if (f) ((float*)p)[i] = v;
    else   ((bf16*)p)[i] = __float2bfloat16(v);
}

// ---------------- dtype detection ----------------
__global__ void detect_kernel(const void* __restrict__ p, int* __restrict__ flag,
                              float* __restrict__ aux) {
    __shared__ int cnt;
    if (threadIdx.x == 0) cnt = 0;
    __syncthreads();
    int bad = 0;
    for (int i = threadIdx.x; i < 1024; i += 256) {
        float v = b2f(((const bf16*)p)[i]);
        if (!(fabsf(v) < 16.0f)) bad++;   // NaN also counts as bad
    }
    if (bad) atomicAdd(&cnt, bad);
    __syncthreads();
    if (threadIdx.x == 0) *flag = (cnt >= 8) ? 1 : 0;
    if (threadIdx.x < BATCH) aux[threadIdx.x] = 0.0f;
}

// ---------------- embedding ----------------
__global__ __launch_bounds__(256) void embed_kernel(const int* __restrict__ tokens,
                                                    const void* __restrict__ emb,
                                                    float* __restrict__ x,
                                                    const int* __restrict__ dflag) {
    int f = *dflag;
    int row = blockIdx.x;                 // b*N + i
    int tok = tokens[row];
    float* xr = x + (size_t)row * D;
    for (int d = threadIdx.x; d < D; d += 256)
        xr[d] = ldf(emb, (size_t)tok * D + d, f);
}

// ---------------- sinusoidal embedding table ----------------
__global__ __launch_bounds__(256) void pe_kernel(float* __restrict__ pe) {
    int r = blockIdx.x;
    int k = threadIdx.x;                  // 0..255 (freq index)
    float t = (float)(N - 1 - r);
    float inv = expf(-(float)k * (9.210340371976184f / 256.0f)); // 10000^{-k/256}
    float s = t * inv;
    pe[(size_t)r * D + k]       = sinf(s);
    pe[(size_t)r * D + 256 + k] = cosf(s);
}

// ---------------- expire span gating (per layer) ----------------
__global__ __launch_bounds__(256) void expire_kernel(const void* __restrict__ mems,
                                                     size_t memOff,
                                                     const int* __restrict__ times_l,
                                                     const void* __restrict__ Wexp,
                                                     size_t wOff,
                                                     const void* __restrict__ bexp,
                                                     size_t bOff,
                                                     float* __restrict__ em,
                                                     float* __restrict__ aux,
                                                     const int* __restrict__ dflag) {
    int f = *dflag;
    int wave = (blockIdx.x * 256 + threadIdx.x) >> 6;  // global j over B*M
    int lane = threadIdx.x & 63;
    int b = wave / M, j = wave % M;
    size_t rbase = memOff + ((size_t)b * M + j) * D;
    float s = 0.0f;
    for (int d = lane; d < D; d += 64)
        s += ldf(mems, rbase + d, f) * ldf(Wexp, wOff + d, f);
    #pragma unroll
    for (int off = 32; off > 0; off >>= 1) s += __shfl_xor(s, off, 64);
    if (lane == 0) {
        s += ldf(bexp, bOff, f);
        float e = 1024.0f / (1.0f + expf(-s));      // sigmoid * MAXMEM
        float t = (float)times_l[b * M + j];
        float emv = (e - t) * (1.0f / 128.0f) + 1.0f;
        emv = fminf(fmaxf(emv, 0.0f), 1.0f);
        em[b * M + j] = emv;
        if (emv > 0.0f && emv < 1.0f)
            atomicAdd(&aux[b], e * (1.0f / (128.0f * 1024.0f)));
    }
}

// ---------------- ctx = concat(mem, x) fp32 ----------------
__global__ __launch_bounds__(256) void ctx_kernel(const void* __restrict__ mems,
                                                  size_t memOff,
                                                  const float* __restrict__ x,
                                                  float* __restrict__ ctx,
                                                  const int* __restrict__ dflag) {
    int f = *dflag;
    size_t idx = (size_t)blockIdx.x * 256 + threadIdx.x;  // over B*CTXLEN*D
    int d = idx & (D - 1);
    size_t rowg = idx >> 9;      // /D
    int p = rowg & (CTXLEN - 1);
    int b = rowg >> 11;          // /CTXLEN
    if (p < M) ctx[idx] = ldf(mems, memOff + ((size_t)b * M + p) * D + d, f);
    else       ctx[idx] = x[((size_t)b * N + (p - M)) * D + d];
}

// ---------------- generic tiled GEMM: C[M,N] = A[M,K](f32) * B[K,N](weights) + bias ----------------
#define BM 64
#define BN 64
#define BK 16
__global__ __launch_bounds__(256) void gemm_kernel(int Mm, int Nn, int Kk,
                                                   const float* __restrict__ A,
                                                   const void* __restrict__ Bw, size_t bwOff,
                                                   const void* __restrict__ bias, size_t biasOff,
                                                   float* __restrict__ C,
                                                   void* __restrict__ Cb,
                                                   int epi,
                                                   const int* __restrict__ dflag) {
    int f = *dflag;
    __shared__ __align__(16) float As[BK][BM + 4];
    __shared__ __align__(16) float Bs[BK][BN + 4];
    int tid = threadIdx.x;
    int bm = blockIdx.y * BM;
    int bn = blockIdx.x * BN;
    int tx = tid & 15, ty = tid >> 4;
    int ka = tid & 15, ma = tid >> 4;   // A loads
    int nb = tid & 63, kb = tid >> 6;   // B loads
    float acc[4][4] = {};
    for (int k0 = 0; k0 < Kk; k0 += BK) {
        #pragma unroll
        for (int p = 0; p < 4; ++p)
            As[ka][ma + 16 * p] = A[(size_t)(bm + ma + 16 * p) * Kk + k0 + ka];
        #pragma unroll
        for (int p = 0; p < 4; ++p)
            Bs[kb + 4 * p][nb] = ldf(Bw, bwOff + (size_t)(k0 + kb + 4 * p) * Nn + bn + nb, f);
        __syncthreads();
        #pragma unroll
        for (int k = 0; k < BK; ++k) {
            float4 a4 = *(const float4*)&As[k][ty * 4];
            float4 b4 = *(const float4*)&Bs[k][tx * 4];
            float a[4] = {a4.x, a4.y, a4.z, a4.w};
            float b[4] = {b4.x, b4.y, b4.z, b4.w};
            #pragma unroll
            for (int i = 0; i < 4; ++i)
                #pragma unroll
                for (int j = 0; j < 4; ++j)
                    acc[i][j] += a[i] * b[j];
        }
        __syncthreads();
    }
    #pragma unroll
    for (int i = 0; i < 4; ++i) {
        int row = bm + ty * 4 + i;
        #pragma unroll
        for (int j = 0; j < 4; ++j) {
            int col = bn + tx * 4 + j;
            float v = acc[i][j];
            if (bias) v += ldf(bias, biasOff + col, f);
            size_t idx = (size_t)row * Nn + col;
            if (epi == 2) v = 0.5f * v * (1.0f + erff(v * 0.70710678118654752f));
            if (Cb) { stf(Cb, idx, f, v); }
            else {
                if (epi == 1) v += C[idx];
                C[idx] = v;
            }
        }
    }
}

// ---------------- flash-tiled attention ----------------
// One block per (b, h, 32-query tile). 256 threads.
// LDS: Qs + KVs(K then V) + Ss + 95-row pos window + gates + m/l/alpha = 63.2 KB
#define AT 32
#define JT 64
__global__ __launch_bounds__(256) void attn_kernel(const float* __restrict__ q,
                                                   const float* __restrict__ kv,
                                                   const float* __restrict__ pos,
                                                   const float* __restrict__ em,
                                                   float* __restrict__ outp) {
    __shared__ __align__(16) float Qs[AT][68];
    __shared__ __align__(16) float KVs[JT][68];
    __shared__ __align__(16) float Ss[AT][65];
    __shared__ __align__(16) float Ps[95][68];
    __shared__ float gates[M];
    __shared__ float mrow[AT], lrow[AT], arow[AT];

    int t = threadIdx.x;
    int bid = blockIdx.x;
    int raw = bid & 31;
    // complementary pairing: blocks (2c,2c+1) -> q-tiles {c, 31-c} (balanced work)
    int it = (raw & 1) ? (31 - (raw >> 1)) : (raw >> 1);
    int h = (bid >> 5) & 7;
    int b = bid >> 8;
    int i0 = it * AT;

    for (int idx = t; idx < AT * 64; idx += 256) {
        int il = idx >> 6, d = idx & 63;
        Qs[il][d] = q[((size_t)(b * N + i0 + il)) * D + h * DH + d];
    }
    for (int idx = t; idx < M; idx += 256) gates[idx] = em[b * M + idx];
    if (t < AT) { mrow[t] = -3e38f; lrow[t] = 0.0f; arow[t] = 0.0f; }

    int ti = t >> 4;       // 0..15 -> rows 2ti+rr
    int tj = t & 15;       // S cols tj+16cc ; PV d-chunk 4tj
    float O[2][4] = {};

    int nx = ((i0 + AT - 1) >> 6) + 1;       // x-region j-tiles
    int ntiles = M / JT + nx;
    for (int tile = 0; tile < ntiles; ++tile) {
        int t0 = tile * JT;
        int t0x = t0 - M;                     // >=0 -> x-region
        __syncthreads();                      // prev PV done with KVs/Ss
        for (int idx = t; idx < JT * 64; idx += 256) {   // K tile
            int jl = idx >> 6, d = idx & 63;
            KVs[jl][d] = kv[((size_t)(b * CTXLEN + t0 + jl)) * (2 * D) + h * DH + d];
        }
        int r0 = N - 1 - (i0 + AT - 1) + t0x;            // pos window base (>=0)
        if (t0x >= 0) {
            for (int idx = t; idx < 95 * 64; idx += 256) {
                int w = idx >> 6, d = idx & 63;
                int r = r0 + w; r = r > (N - 1) ? (N - 1) : r;
                Ps[w][d] = pos[(size_t)r * DH + d];
            }
        }
        __syncthreads();
        // ---- S = Q K^T (+ pos), rows il=2ti+rr, cols jl=tj+16cc ----
        float s[2][4] = {};
        #pragma unroll
        for (int d4 = 0; d4 < 16; ++d4) {
            float4 qv[2], kv4[4];
            #pragma unroll
            for (int rr = 0; rr < 2; ++rr) qv[rr] = *(const float4*)&Qs[2 * ti + rr][4 * d4];
            #pragma unroll
            for (int cc = 0; cc < 4; ++cc) kv4[cc] = *(const float4*)&KVs[tj + 16 * cc][4 * d4];
            #pragma unroll
            for (int rr = 0; rr < 2; ++rr)
                #pragma unroll
                for (int cc = 0; cc < 4; ++cc)
                    s[rr][cc] += qv[rr].x * kv4[cc].x + qv[rr].y * kv4[cc].y
                               + qv[rr].z * kv4[cc].z + qv[rr].w * kv4[cc].w;
        }
        if (t0x >= 0) {
            #pragma unroll 4
            for (int d4 = 0; d4 < 16; ++d4) {
                float4 qv[2];
                #pragma unroll
                for (int rr = 0; rr < 2; ++rr) qv[rr] = *(const float4*)&Qs[2 * ti + rr][4 * d4];
                #pragma unroll
                for (int rr = 0; rr < 2; ++rr) {
                    int wb = (AT - 1) - (2 * ti + rr);   // w = jl + (AT-1) - il
                    #pragma unroll
                    for (int cc = 0; cc < 4; ++cc) {
                        float4 pv = *(const float4*)&Ps[tj + 16 * cc + wb][4 * d4];
                        s[rr][cc] += qv[rr].x * pv.x + qv[rr].y * pv.y
                                   + qv[rr].z * pv.z + qv[rr].w * pv.w;
                    }
                }
            }
        }
        #pragma unroll
        for (int rr = 0; rr < 2; ++rr) {
            int il = 2 * ti + rr;
            #pragma unroll
            for (int cc = 0; cc < 4; ++cc) {
                int jl = tj + 16 * cc;
                float v = s[rr][cc] * 0.125f;            // DH^-0.5
                if (t0x >= 0 && (t0x + jl) > (i0 + il)) v = -3e38f;  // causal mask
                Ss[il][jl] = v;
            }
        }
        __syncthreads();                      // Ss ready, K consumed
        for (int idx = t; idx < JT * 64; idx += 256) {   // V tile (overwrite K)
            int jl = idx >> 6, d = idx & 63;
            KVs[jl][d] = kv[((size_t)(b * CTXLEN + t0 + jl)) * (2 * D) + D + h * DH + d];
        }
        // ---- online softmax row update (one thread per row) ----
        if (t < AT) {
            int il = t;
            float mo = mrow[il];
            float tmax = -3e38f;
            for (int j = 0; j < JT; ++j) tmax = fmaxf(tmax, Ss[il][j]);
            float mn = fmaxf(mo, tmax);
            float alpha = expf(mo - mn);
            float sum = 0.0f;
            for (int j = 0; j < JT; ++j) {
                float e = expf(Ss[il][j] - mn);
                sum += e;                                 // ungated denominator
                int jg = t0 + j;
                float g = (jg < M) ? gates[jg] : 1.0f;    // post-softmax expire gate
                Ss[il][j] = e * g;
            }
            lrow[il] = lrow[il] * alpha + sum;
            mrow[il] = mn;
            arow[il] = alpha;
        }
        __syncthreads();
        // ---- PV accumulate: rows 2ti+rr, d = 4tj+dd ----
        float a0 = arow[2 * ti], a1 = arow[2 * ti + 1];
        #pragma unroll
        for (int dd = 0; dd < 4; ++dd) { O[0][dd] *= a0; O[1][dd] *= a1; }
        #pragma unroll
        for (int jb = 0; jb < 16; ++jb) {
            float4 p0 = *(const float4*)&Ss[2 * ti][4 * jb];
            float4 p1 = *(const float4*)&Ss[2 * ti + 1][4 * jb];
            float4 v0 = *(const float4*)&KVs[4 * jb + 0][4 * tj];
            float4 v1 = *(const float4*)&KVs[4 * jb + 1][4 * tj];
            float4 v2 = *(const float4*)&KVs[4 * jb + 2][4 * tj];
            float4 v3 = *(const float4*)&KVs[4 * jb + 3][4 * tj];
            O[0][0] += p0.x * v0.x + p0.y * v1.x + p0.z * v2.x + p0.w * v3.x;
            O[0][1] += p0.x * v0.y + p0.y * v1.y + p0.z * v2.y + p0.w * v3.y;
            O[0][2] += p0.x * v0.z + p0.y * v1.z + p0.z * v2.z + p0.w * v3.z;
            O[0][3] += p0.x * v0.w + p0.y * v1.w + p0.z * v2.w + p0.w * v3.w;
            O[1][0] += p1.x * v0.x + p1.y * v1.x + p1.z * v2.x + p1.w * v3.x;
            O[1][1] += p1.x * v0.y + p1.y * v1.y + p1.z * v2.y + p1.w * v3.y;
            O[1][2] += p1.x * v0.z + p1.y * v1.z + p1.z * v2.z + p1.w * v3.z;
            O[1][3] += p1.x * v0.w + p1.y * v1.w + p1.z * v2.w + p1.w * v3.w;
        }
    }
    #pragma unroll
    for (int rr = 0; rr < 2; ++rr) {
        int il = 2 * ti + rr;
        float inv = 1.0f / lrow[il];
        float4 r4;
        r4.x = O[rr][0] * inv; r4.y = O[rr][1] * inv;
        r4.z = O[rr][2] * inv; r4.w = O[rr][3] * inv;
        *(float4*)&outp[((size_t)(b * N + i0 + il)) * D + h * DH + 4 * tj] = r4;
    }
}

// ---------------- final layernorm ----------------
__global__ __launch_bounds__(256) void ln_kernel(const float* __restrict__ x,
                                                 const void* __restrict__ g,
                                                 const void* __restrict__ bta,
                                                 float* __restrict__ y,
                                                 const int* __restrict__ dflag) {
    int f = *dflag;
    int row = blockIdx.x;
    const float* xr = x + (size_t)row * D;
    __shared__ float red[4];
    int lane = threadIdx.x & 63, wv = threadIdx.x >> 6;
    float s = 0.0f;
    for (int d = threadIdx.x; d < D; d += 256) s += xr[d];
    #pragma unroll
    for (int off = 32; off > 0; off >>= 1) s += __shfl_xor(s, off, 64);
    if (lane == 0) red[wv] = s;
    __syncthreads();
    float mu = (red[0] + red[1] + red[2] + red[3]) * (1.0f / D);
    __syncthreads();
    float v = 0.0f;
    for (int d = threadIdx.x; d < D; d += 256) { float tt = xr[d] - mu; v += tt * tt; }
    #pragma unroll
    for (int off = 32; off > 0; off >>= 1) v += __shfl_xor(v, off, 64);
    if (lane == 0) red[wv] = v;
    __syncthreads();
    float var = (red[0] + red[1] + red[2] + red[3]) * (1.0f / D);
    float rstd = 1.0f / sqrtf(var + 1e-5f);
    for (int d = threadIdx.x; d < D; d += 256)
        y[(size_t)row * D + d] = (xr[d] - mu) * rstd * ldf(g, d, f) + ldf(bta, d, f);
}

// ---------------- aux write ----------------
__global__ void write_aux_kernel(const float* __restrict__ aux, void* __restrict__ out,
                                 const int* __restrict__ dflag) {
    int f = *dflag;
    if (threadIdx.x < BATCH)
        stf(out, (size_t)ROWS * V + threadIdx.x, f, aux[threadIdx.x]);
}

extern "C" void kernel_launch(void* const* d_in, const int* in_sizes, int n_in,
                              void* d_out, int out_size, void* d_ws, size_t ws_size,
                              hipStream_t stream) {
    (void)in_sizes; (void)n_in; (void)out_size; (void)ws_size;
    const int*  tokens  = (const int*)d_in[0];
    const void* mems    = d_in[1];
    const int*  times   = (const int*)d_in[2];
    const void* tok_emb = d_in[3];
    const void* Wq   = d_in[4];
    const void* bq   = d_in[5];
    const void* Wkv  = d_in[6];
    const void* bkv  = d_in[7];
    const void* Wo   = d_in[8];
    const void* bo   = d_in[9];
    const void* Wpos = d_in[10];
    const void* bpos = d_in[11];
    const void* Wexp = d_in[12];
    const void* bexp = d_in[13];
    const void* W1   = d_in[14];
    const void* b1   = d_in[15];
    const void* W2   = d_in[16];
    const void* b2v  = d_in[17];
    const void* ln_g = d_in[18];
    const void* ln_b = d_in[19];
    const void* Whead= d_in[20];

    float* ws  = (float*)d_ws;
    float* x    = ws;                            // ROWS*D
    float* pe   = x    + (size_t)ROWS * D;       // N*D
    float* ctx  = pe   + (size_t)N * D;          // CROWS*D   (y aliases)
    float* kv   = ctx  + (size_t)CROWS * D;      // CROWS*2D  (h1 aliases)
    float* q    = kv   + (size_t)CROWS * 2 * D;  // ROWS*D
    float* pos  = q    + (size_t)ROWS * D;       // N*DH
    float* em   = pos  + (size_t)N * DH;         // B*M
    float* aout = em   + (size_t)BATCH * M;      // ROWS*D
    float* aux  = aout + (size_t)ROWS * D;       // 2
    int*   flag = (int*)(aux + 2);
    float* h1   = kv;   // alias
    float* y    = ctx;  // alias

    detect_kernel<<<1, 256, 0, stream>>>(tok_emb, flag, aux);
    embed_kernel<<<ROWS, 256, 0, stream>>>(tokens, tok_emb, x, flag);
    pe_kernel<<<N, 256, 0, stream>>>(pe);

    for (int l = 0; l < DEPTH; ++l) {
        expire_kernel<<<(BATCH * M) / 4, 256, 0, stream>>>(
            mems, (size_t)l * BATCH * M * D, times + (size_t)l * BATCH * M,
            Wexp, (size_t)l * D, bexp, (size_t)l, em, aux, flag);
        ctx_kernel<<<(BATCH * CTXLEN * D) / 256, 256, 0, stream>>>(
            mems, (size_t)l * BATCH * M * D, x, ctx, flag);
        gemm_kernel<<<dim3(D / BN, ROWS / BM), 256, 0, stream>>>(
            ROWS, D, D, x, Wq, (size_t)l * D * D, bq, (size_t)l * D, q, nullptr, 0, flag);
        gemm_kernel<<<dim3(2 * D / BN, CROWS / BM), 256, 0, stream>>>(
            CROWS, 2 * D, D, ctx, Wkv, (size_t)l * D * 2 * D, bkv, (size_t)l * 2 * D, kv, nullptr, 0, flag);
        gemm_kernel<<<dim3(DH / BN, N / BM), 256, 0, stream>>>(
            N, DH, D, pe, Wpos, (size_t)l * D * DH, bpos, (size_t)l * DH, pos, nullptr, 0, flag);
        attn_kernel<<<BATCH * H * (N / AT), 256, 0, stream>>>(q, kv, pos, em, aout);
        gemm_kernel<<<dim3(D / BN, ROWS / BM), 256, 0, stream>>>(
            ROWS, D, D, aout, Wo, (size_t)l * D * D, bo, (size_t)l * D, x, nullptr, 1, flag);
        gemm_kernel<<<dim3(4 * D / BN, ROWS / BM), 256, 0, stream>>>(
            ROWS, 4 * D, D, x, W1, (size_t)l * D * 4 * D, b1, (size_t)l * 4 * D, h1, nullptr, 2, flag);
        gemm_kernel<<<dim3(D / BN, ROWS / BM), 256, 0, stream>>>(
            ROWS, D, 4 * D, h1, W2, (size_t)l * 4 * D * D, b2v, (size_t)l * D, x, nullptr, 1, flag);
    }

    ln_kernel<<<ROWS, 256, 0, stream>>>(x, ln_g, ln_b, y, flag);
    gemm_kernel<<<dim3(V / BN, ROWS / BM), 256, 0, stream>>>(
        ROWS, V, D, y, Whead, 0, nullptr, 0, nullptr, d_out, 0, flag);
    write_aux_kernel<<<1, 64, 0, stream>>>(aux, d_out, flag);
}